// Round 6
// baseline (318.561 us; speedup 1.0000x reference)
//
#include <hip/hip_runtime.h>

#define Bdim 8
#define Tdim 100
#define Sdim 400
#define Kk   8
#define Hdim 512
#define Vdim 32000
#define Mdim 800          // B*T
#define VCHUNK 4000       // vocab slice per combine block

typedef __attribute__((ext_vector_type(8))) short short8;     // 8 bf16 = 4 VGPRs
typedef __attribute__((ext_vector_type(4))) short short4v;    // 4 bf16 = 2 VGPRs
typedef __attribute__((ext_vector_type(4))) float float4_t;   // MFMA acc

static __device__ __forceinline__ unsigned short f2bf(float f) {
    unsigned int x = __float_as_uint(f);
    return (unsigned short)((x + 0x7fffu + ((x >> 16) & 1u)) >> 16);   // RNE
}
static __device__ __forceinline__ float bf2f(unsigned short h) {
    return __uint_as_float(((unsigned int)h) << 16);
}

// async 16B global->LDS (wave-uniform LDS base + lane*16)
static __device__ __forceinline__ void gload_lds16(const void* g, void* s) {
    __builtin_amdgcn_global_load_lds((const __attribute__((address_space(1))) void*)g,
                                     (__attribute__((address_space(3))) void*)s, 16, 0, 0);
}

// ---------------- prep: dec_out fp32 -> bf16 (vectorized x4); also zeros rowsum ----------------
__global__ void convert_a_kernel(const float* __restrict__ A, unsigned short* __restrict__ Abf,
                                 float* __restrict__ rowsum, int n4) {
    int i = blockIdx.x * blockDim.x + threadIdx.x;
    if (i < Mdim) rowsum[i] = 0.f;
    if (i < n4) {
        float4 f = ((const float4*)A)[i];
        short4v s;
        s[0] = (short)f2bf(f.x); s[1] = (short)f2bf(f.y);
        s[2] = (short)f2bf(f.z); s[3] = (short)f2bf(f.w);
        *(short4v*)(Abf + i * 4) = s;
    }
}

// ---------------- prep: W (512 x 32000) fp32 -> WT (32000 x 512) bf16 ----------------
__global__ __launch_bounds__(256) void transpose_kernel(const float* __restrict__ W,
                                                        unsigned short* __restrict__ WT) {
    __shared__ float tile[64][65];
    const int k0 = blockIdx.y * 64;
    const int v0 = blockIdx.x * 64;
    const int t  = threadIdx.x;
    const int tx = t & 15;            // float4 col within tile row
    const int ty = t >> 4;            // 0..15
#pragma unroll
    for (int i = 0; i < 64; i += 16) {
        float4 f = *(const float4*)&W[(size_t)(k0 + ty + i) * Vdim + v0 + tx * 4];
        tile[ty + i][tx * 4 + 0] = f.x;
        tile[ty + i][tx * 4 + 1] = f.y;
        tile[ty + i][tx * 4 + 2] = f.z;
        tile[ty + i][tx * 4 + 3] = f.w;
    }
    __syncthreads();
    const int c = t & 7;              // k-chunk of 8
    const int v = t >> 3;             // 0..31
#pragma unroll
    for (int i = 0; i < 64; i += 32) {
        short8 s;
#pragma unroll
        for (int j = 0; j < 8; ++j) s[j] = (short)f2bf(tile[c * 8 + j][v + i]);
        *(short8*)&WT[(size_t)(v0 + v + i) * Hdim + k0 + c * 8] = s;
    }
}

// ---------------- GEMM: logits(800x32000) = Abf * WT^T + bias; bf16 store + row sumexp ----
// Round-6: barrier-free K-loop. Diagnosis: every structure with a barrier per 64-K step
// lands 77-121 us with all pipes <20% -- the barrier mechanism itself is the bottleneck.
// K=512 is small: stage the WHOLE A-tile (128x512 bf16 = 128 KB LDS) once, ONE
// __syncthreads(), then 16 K-steps of pure compute with ZERO barriers. B-fragments are
// loaded per-lane directly from global WT (L2/L3-resident, 16 rows x 64B per instr) into
// a depth-4 register ring that hides L2 latency under ~3 K-steps of MFMA.
// Block 128m x 256n, 8 waves (2m x 4n), per-wave 64x64, acc[4][4] -- fragment layout,
// XOR swizzle and epilogue identical to the verified R2 kernel. 1 block/CU (128 KB LDS).
__global__ __launch_bounds__(512, 2) void gemm_kernel(const unsigned short* __restrict__ Abf,
                                                      const unsigned short* __restrict__ WT,
                                                      const float* __restrict__ bias,
                                                      unsigned short* __restrict__ logitsbf,
                                                      float* __restrict__ rowsum) {
    __shared__ __align__(16) unsigned short As[128 * 512];   // 128 KB

    const int tid  = threadIdx.x;
    const int lane = tid & 63;
    const int wave = tid >> 6;             // 0..7
    const int l15  = lane & 15;
    const int kq   = lane >> 4;            // 0..3

    // bijective XCD swizzle (m204): nwg = 7 m * 125 n = 875
    const int NWG = 875;
    const int orig = blockIdx.x;
    const int xcd = orig & 7;
    const int q8  = NWG >> 3;              // 109
    const int r8  = NWG & 7;               // 3
    const int wg  = (xcd < r8 ? xcd * (q8 + 1) : r8 * (q8 + 1) + (xcd - r8) * q8) + (orig >> 3);
    const int m_blk = (wg % 7) * 128;      // m-fastest: B-panel reuse is L2-local
    const int n_blk = (wg / 7) * 256;

    const int wm = wave & 1, wn = wave >> 1;   // 2m x 4n waves
    const int m0 = wm * 64, n0 = wn * 64;

    // B row pointers (global, L2-resident): rows n_blk+n0+j*16+l15, this lane's k-slice
    const unsigned short* bptr[4];
#pragma unroll
    for (int j = 0; j < 4; ++j)
        bptr[j] = WT + (size_t)(n_blk + n0 + j * 16 + l15) * Hdim + kq * 8;

    // B prefetch ring, depth 4 (hides ~300cy L2 latency under ~3 K-steps of MFMA)
    short8 bp[4][4];
#pragma unroll
    for (int t = 0; t < 4; ++t)
#pragma unroll
        for (int j = 0; j < 4; ++j)
            bp[t][j] = *(const short8*)(bptr[j] + t * 32);

    // stage full A tile (128 x 512) once: 16 chunks/thread, XOR-swizzled source so
    // linear gload_lds dest yields conflict-free swizzled fragment reads
#pragma unroll
    for (int q = 0; q < 16; ++q) {
        int slot = q * 512 + tid;          // 16B-chunk slot, 8192 total
        int row  = slot >> 6;              // 0..127
        int c    = slot & 63;              // k-chunk within row
        int gc   = (c & ~7) | ((c ^ row) & 7);
        int arow = m_blk + row; if (arow >= Mdim) arow = Mdim - 1;   // clamp; epilogue masks
        gload_lds16(Abf + (size_t)arow * Hdim + gc * 8,
                    As + (size_t)(q * 512 + wave * 64) * 8);         // wave-uniform base
    }

    // a-frag base offsets (shorts): row*512 + swz-chunk*8, parity p = t&1
    int abase[4][2];
#pragma unroll
    for (int i = 0; i < 4; ++i) {
        int row = m0 + i * 16 + l15;
#pragma unroll
        for (int p = 0; p < 2; ++p)
            abase[i][p] = row * 512 + (((p * 4 + kq) ^ (row & 7)) * 8);
    }

    float4_t acc[4][4] = {};

    __syncthreads();     // drains gload_lds (vmcnt 0); publishes As. The ONLY barrier.

#pragma unroll
    for (int t = 0; t < 16; ++t) {
        short8 af[4];
#pragma unroll
        for (int i = 0; i < 4; ++i)
            af[i] = *(const short8*)(As + abase[i][t & 1] + (t >> 1) * 64);
#pragma unroll
        for (int i = 0; i < 4; ++i)
#pragma unroll
            for (int j = 0; j < 4; ++j)
                acc[i][j] = __builtin_amdgcn_mfma_f32_16x16x32_bf16(af[i], bp[t & 3][j], acc[i][j], 0, 0, 0);
        if (t + 4 < 16) {                  // refill ring slot just freed (WAR-ordered by compiler)
#pragma unroll
            for (int j = 0; j < 4; ++j)
                bp[t & 3][j] = *(const short8*)(bptr[j] + (t + 4) * 32);
        }
    }

    // epilogue: bias add, bf16 store, per-row partial sum of exp -> atomicAdd rowsum
    float bj[4];
#pragma unroll
    for (int j = 0; j < 4; ++j) bj[j] = bias[n_blk + n0 + j * 16 + l15];

#pragma unroll
    for (int i = 0; i < 4; ++i) {
        float se[4] = {0.f, 0.f, 0.f, 0.f};
        int grow0 = m_blk + m0 + i * 16 + kq * 4;      // + r
#pragma unroll
        for (int j = 0; j < 4; ++j) {
            int col = n_blk + n0 + j * 16 + l15;
#pragma unroll
            for (int r = 0; r < 4; ++r) {
                float v = acc[i][j][r] + bj[j];
                se[r] += __expf(v);
                if (grow0 + r < Mdim)
                    logitsbf[(size_t)(grow0 + r) * Vdim + col] = f2bf(v);
            }
        }
#pragma unroll
        for (int r = 0; r < 4; ++r) {
#pragma unroll
            for (int off = 8; off; off >>= 1)
                se[r] += __shfl_xor(se[r], off, 64);   // reduce over the 16 cols (l15)
        }
        if (l15 == 0) {
#pragma unroll
            for (int r = 0; r < 4; ++r)
                if (grow0 + r < Mdim) atomicAdd(&rowsum[grow0 + r], se[r]);
        }
    }
}

// ---------------- combine: sparse copy-dist scatter + log blend ----------------
__global__ __launch_bounds__(256) void combine_kernel(const unsigned short* __restrict__ logitsbf,
                                                      const float* __restrict__ weights,
                                                      const float* __restrict__ p_trans,
                                                      const float* __restrict__ trans_probs,
                                                      const float* __restrict__ probs,
                                                      const int* __restrict__ idxes,
                                                      const float* __restrict__ rowsum,
                                                      float* __restrict__ out) {
    __shared__ __align__(16) float ts[VCHUNK];

    const int bt  = blockIdx.x;          // 0..799
    const int c   = blockIdx.y;          // 0..7
    const int b   = bt / Tdim;
    const int tid = threadIdx.x;
    const int v0  = c * VCHUNK;

    const float pt = p_trans[bt];
    const float c1 = (1.f - pt) / rowsum[bt];

    float4* ts4 = (float4*)ts;
    const float4 z = make_float4(0.f, 0.f, 0.f, 0.f);
#pragma unroll
    for (int i = tid; i < VCHUNK / 4; i += 256) ts4[i] = z;
    __syncthreads();

    for (int i = tid; i < Sdim * Kk; i += 256) {
        float pv  = probs[b * (Sdim * Kk) + i];
        float tpv = trans_probs[b * (Sdim * Kk) + i];
        int   idx = idxes[b * (Sdim * Kk) + i];
        int   rel = idx - v0;
        if (pv > 0.05f && (unsigned)rel < (unsigned)VCHUNK) {
            float w = weights[bt * Sdim + (i >> 3)];
            atomicAdd(&ts[rel], w * tpv);
        }
    }
    __syncthreads();

    const short8* lrow8 = (const short8*)(logitsbf + (size_t)bt * Vdim + v0);
    float4* out4 = (float4*)(out + (size_t)bt * Vdim + v0);
#pragma unroll
    for (int i = tid; i < VCHUNK / 8; i += 256) {
        short8 x8 = lrow8[i];
        float4 t0 = ts4[i * 2];
        float4 t1 = ts4[i * 2 + 1];
        float4 o0, o1;
        o0.x = __logf(pt * t0.x + c1 * __expf(bf2f((unsigned short)x8[0])));
        o0.y = __logf(pt * t0.y + c1 * __expf(bf2f((unsigned short)x8[1])));
        o0.z = __logf(pt * t0.z + c1 * __expf(bf2f((unsigned short)x8[2])));
        o0.w = __logf(pt * t0.w + c1 * __expf(bf2f((unsigned short)x8[3])));
        o1.x = __logf(pt * t1.x + c1 * __expf(bf2f((unsigned short)x8[4])));
        o1.y = __logf(pt * t1.y + c1 * __expf(bf2f((unsigned short)x8[5])));
        o1.z = __logf(pt * t1.z + c1 * __expf(bf2f((unsigned short)x8[6])));
        o1.w = __logf(pt * t1.w + c1 * __expf(bf2f((unsigned short)x8[7])));
        out4[i * 2]     = o0;
        out4[i * 2 + 1] = o1;
    }
}

extern "C" void kernel_launch(void* const* d_in, const int* in_sizes, int n_in,
                              void* d_out, int out_size, void* d_ws, size_t ws_size,
                              hipStream_t stream) {
    const float* dec_out     = (const float*)d_in[0];   // (8,100,512)
    const float* W           = (const float*)d_in[1];   // (512,32000)
    const float* bias        = (const float*)d_in[2];   // (32000,)
    const float* weights     = (const float*)d_in[3];   // (8,100,400)
    const float* p_trans     = (const float*)d_in[4];   // (8,100,1)
    const float* trans_probs = (const float*)d_in[5];   // (8,400,8)
    const float* probs       = (const float*)d_in[6];   // (8,400,8)
    const int*   idxes       = (const int*)d_in[7];     // (8,400,8)
    float* out = (float*)d_out;

    char* wsb = (char*)d_ws;
    unsigned short* Abf      = (unsigned short*)wsb;                      // 819,200 B
    unsigned short* WT       = (unsigned short*)(wsb + (1ull << 20));     // 32.8 MB
    unsigned short* logitsbf = (unsigned short*)(wsb + (35ull << 20));    // 51.2 MB
    float*          rowsum   = (float*)(wsb + (90ull << 20));             // 3200 B

    convert_a_kernel<<<dim3((Mdim * Hdim / 4 + 255) / 256), dim3(256), 0, stream>>>(dec_out, Abf, rowsum, Mdim * Hdim / 4);
    transpose_kernel<<<dim3(Vdim / 64, Hdim / 64), dim3(256), 0, stream>>>(W, WT);
    gemm_kernel<<<dim3(875), dim3(512), 0, stream>>>(Abf, WT, bias, logitsbf, rowsum);
    combine_kernel<<<dim3(Mdim, Vdim / VCHUNK), dim3(256), 0, stream>>>(logitsbf, weights, p_trans, trans_probs,
                                                                        probs, idxes, rowsum, out);
}

// Round 8
// 283.461 us; speedup vs baseline: 1.1238x; 1.1238x over previous
//
#include <hip/hip_runtime.h>

#define Bdim 8
#define Tdim 100
#define Sdim 400
#define Kk   8
#define Hdim 512
#define Vdim 32000
#define Mdim 800          // B*T
#define VCHUNK 4000       // vocab slice per combine block

typedef __attribute__((ext_vector_type(8))) short short8;     // 8 bf16 = 4 VGPRs
typedef __attribute__((ext_vector_type(4))) short short4v;    // 4 bf16 = 2 VGPRs
typedef __attribute__((ext_vector_type(4))) float float4_t;   // MFMA acc

static __device__ __forceinline__ unsigned short f2bf(float f) {
    unsigned int x = __float_as_uint(f);
    return (unsigned short)((x + 0x7fffu + ((x >> 16) & 1u)) >> 16);   // RNE
}
static __device__ __forceinline__ float bf2f(unsigned short h) {
    return __uint_as_float(((unsigned int)h) << 16);
}

// async 16B global->LDS (wave-uniform LDS base + lane*16)
static __device__ __forceinline__ void gload_lds16(const void* g, void* s) {
    __builtin_amdgcn_global_load_lds((const __attribute__((address_space(1))) void*)g,
                                     (__attribute__((address_space(3))) void*)s, 16, 0, 0);
}

// ---------------- prep: dec_out fp32 -> bf16 (vectorized x4); also zeros rowsum ----------------
__global__ void convert_a_kernel(const float* __restrict__ A, unsigned short* __restrict__ Abf,
                                 float* __restrict__ rowsum, int n4) {
    int i = blockIdx.x * blockDim.x + threadIdx.x;
    if (i < Mdim) rowsum[i] = 0.f;
    if (i < n4) {
        float4 f = ((const float4*)A)[i];
        short4v s;
        s[0] = (short)f2bf(f.x); s[1] = (short)f2bf(f.y);
        s[2] = (short)f2bf(f.z); s[3] = (short)f2bf(f.w);
        *(short4v*)(Abf + i * 4) = s;
    }
}

// ---------------- prep: W (512 x 32000) fp32 -> WT (32000 x 512) bf16 ----------------
__global__ __launch_bounds__(256) void transpose_kernel(const float* __restrict__ W,
                                                        unsigned short* __restrict__ WT) {
    __shared__ float tile[64][65];
    const int k0 = blockIdx.y * 64;
    const int v0 = blockIdx.x * 64;
    const int t  = threadIdx.x;
    const int tx = t & 15;            // float4 col within tile row
    const int ty = t >> 4;            // 0..15
#pragma unroll
    for (int i = 0; i < 64; i += 16) {
        float4 f = *(const float4*)&W[(size_t)(k0 + ty + i) * Vdim + v0 + tx * 4];
        tile[ty + i][tx * 4 + 0] = f.x;
        tile[ty + i][tx * 4 + 1] = f.y;
        tile[ty + i][tx * 4 + 2] = f.z;
        tile[ty + i][tx * 4 + 3] = f.w;
    }
    __syncthreads();
    const int c = t & 7;              // k-chunk of 8
    const int v = t >> 3;             // 0..31
#pragma unroll
    for (int i = 0; i < 64; i += 32) {
        short8 s;
#pragma unroll
        for (int j = 0; j < 8; ++j) s[j] = (short)f2bf(tile[c * 8 + j][v + i]);
        *(short8*)&WT[(size_t)(v0 + v + i) * Hdim + k0 + c * 8] = s;
    }
}

// ---------------- GEMM: logits(800x32000) = Abf * WT^T + bias; bf16 store + row sumexp ----
// Round-8: R7 depth-2 pipeline with the last-iteration drain FIXED.
// R7 bug: at kt=7 only stage(7)'s 8 loads are outstanding, so vmcnt(8) was satisfied
// immediately and compute(7) raced the in-flight DMA (absmax 1.375). Final iteration
// must drain vmcnt(0); kt is compile-time under full unroll so the branch folds.
//   prologue: stage(0)->buf0, stage(1)->buf1
//   per kt:  vmcnt(8) [kt<7] / vmcnt(0) [kt==7]   -> stage(kt) provably retired
//            s_barrier -> compute(kt) -> s_barrier -> stage(kt+2) [kt<6]
__global__ __launch_bounds__(256) void gemm_kernel(const unsigned short* __restrict__ Abf,
                                                   const unsigned short* __restrict__ WT,
                                                   const float* __restrict__ bias,
                                                   unsigned short* __restrict__ logitsbf,
                                                   float* __restrict__ rowsum) {
    __shared__ __align__(16) unsigned short As[2 * 128 * 64];   // 2 x 16 KB
    __shared__ __align__(16) unsigned short Bs[2 * 128 * 64];   // 2 x 16 KB

    const int tid  = threadIdx.x;
    const int lane = tid & 63;
    const int wave = tid >> 6;
    const int l15  = lane & 15;
    const int kq   = lane >> 4;            // 0..3

    // bijective XCD swizzle (m204): nwg = 7*250 = 1750
    const int NWG = 7 * 250;
    const int orig = blockIdx.x;
    const int xcd = orig & 7;
    const int q8  = NWG >> 3;              // 218
    const int r8  = NWG & 7;               // 6
    const int wg  = (xcd < r8 ? xcd * (q8 + 1) : r8 * (q8 + 1) + (xcd - r8) * q8) + (orig >> 3);
    const int m_blk = (wg % 7) * 128;      // m-fastest: B-panel reuse is L2-local
    const int n_blk = (wg / 7) * 128;

    const int wm = wave & 1, wn = wave >> 1;
    const int m0 = wm * 64, n0 = wn * 64;

    // staging: 1024 16B-chunks per matrix; chunk = (q*4+wave)*64 + lane
    const unsigned short* agp[4];
    const unsigned short* bgp[4];
    int lslot[4];
#pragma unroll
    for (int q = 0; q < 4; ++q) {
        int chunk = (q * 4 + wave) * 64 + lane;
        int row = chunk >> 3, c = chunk & 7;
        int gc  = c ^ (row & 7);                 // XOR swizzle: lane fetches the chunk that
        int arow = m_blk + row;                  // belongs at its contiguous LDS slot
        if (arow >= Mdim) arow = Mdim - 1;       // clamp; epilogue masks
        agp[q] = Abf + (size_t)arow * Hdim + gc * 8;
        bgp[q] = WT + (size_t)(n_blk + row) * Hdim + gc * 8;
        lslot[q] = (q * 4 + wave) * 512;         // wave-uniform base (shorts)
    }

    // fragment LDS offsets (shorts): row*64 + ((ks*4+kq)^(row&7))*8
    int a_off[2][4], b_off[2][4];
#pragma unroll
    for (int ks = 0; ks < 2; ++ks)
#pragma unroll
        for (int i = 0; i < 4; ++i) {
            int ra = m0 + i * 16 + l15;
            a_off[ks][i] = ra * 64 + (((ks * 4 + kq) ^ (ra & 7)) * 8);
            int rb = n0 + i * 16 + l15;
            b_off[ks][i] = rb * 64 + (((ks * 4 + kq) ^ (rb & 7)) * 8);
        }

    float4_t acc[4][4] = {};

    // prologue: stage K-tiles 0 and 1 into buffers 0 and 1
#pragma unroll
    for (int q = 0; q < 4; ++q) {
        gload_lds16(agp[q], As + lslot[q]);
        gload_lds16(bgp[q], Bs + lslot[q]);
    }
#pragma unroll
    for (int q = 0; q < 4; ++q) {
        gload_lds16(agp[q] + 64, As + 8192 + lslot[q]);
        gload_lds16(bgp[q] + 64, Bs + 8192 + lslot[q]);
    }

#pragma unroll
    for (int kt = 0; kt < 8; ++kt) {
        const int cur = kt & 1;
        // stage(kt) must be retired before compute(kt). For kt<7 there are >8 loads in
        // flight so vmcnt(8) pins exactly stage(kt); at kt==7 only stage(7)'s 8 remain,
        // so the wait must be vmcnt(0) (R7's bug: vmcnt(8) passed immediately -> race).
        if (kt == 7) asm volatile("s_waitcnt vmcnt(0)" ::: "memory");
        else         asm volatile("s_waitcnt vmcnt(8)" ::: "memory");
        __builtin_amdgcn_s_barrier();            // buf(cur) now valid across all waves
        __builtin_amdgcn_sched_barrier(0);
        const unsigned short* Ab = As + cur * 8192;
        const unsigned short* Bb = Bs + cur * 8192;
#pragma unroll
        for (int ks = 0; ks < 2; ++ks) {
            short8 af[4], bfr[4];
#pragma unroll
            for (int i = 0; i < 4; ++i) af[i]  = *(const short8*)(Ab + a_off[ks][i]);
#pragma unroll
            for (int j = 0; j < 4; ++j) bfr[j] = *(const short8*)(Bb + b_off[ks][j]);
#pragma unroll
            for (int i = 0; i < 4; ++i)
#pragma unroll
                for (int j = 0; j < 4; ++j)
                    acc[i][j] = __builtin_amdgcn_mfma_f32_16x16x32_bf16(af[i], bfr[j], acc[i][j], 0, 0, 0);
        }
        if (kt < 7) __builtin_amdgcn_s_barrier();  // all waves done reading buf(cur)
        if (kt < 6) {                              // stage(kt+2) -> buf(cur), WAR-safe
            const int ko = (kt + 2) * 64;
#pragma unroll
            for (int q = 0; q < 4; ++q) {
                gload_lds16(agp[q] + ko, As + cur * 8192 + lslot[q]);
                gload_lds16(bgp[q] + ko, Bs + cur * 8192 + lslot[q]);
            }
        }
    }

    // epilogue: bias add, bf16 store, per-row partial sum of exp -> atomicAdd rowsum
    float bj[4];
#pragma unroll
    for (int j = 0; j < 4; ++j) bj[j] = bias[n_blk + n0 + j * 16 + l15];

#pragma unroll
    for (int i = 0; i < 4; ++i) {
        float se[4] = {0.f, 0.f, 0.f, 0.f};
        int grow0 = m_blk + m0 + i * 16 + kq * 4;      // + r
#pragma unroll
        for (int j = 0; j < 4; ++j) {
            int col = n_blk + n0 + j * 16 + l15;
#pragma unroll
            for (int r = 0; r < 4; ++r) {
                float v = acc[i][j][r] + bj[j];
                se[r] += __expf(v);
                if (grow0 + r < Mdim)
                    logitsbf[(size_t)(grow0 + r) * Vdim + col] = f2bf(v);
            }
        }
#pragma unroll
        for (int r = 0; r < 4; ++r) {
#pragma unroll
            for (int off = 8; off; off >>= 1)
                se[r] += __shfl_xor(se[r], off, 64);   // reduce over the 16 cols (l15)
        }
        if (l15 == 0) {
#pragma unroll
            for (int r = 0; r < 4; ++r)
                if (grow0 + r < Mdim) atomicAdd(&rowsum[grow0 + r], se[r]);
        }
    }
}

// ---------------- combine: sparse copy-dist scatter + log blend ----------------
__global__ __launch_bounds__(256) void combine_kernel(const unsigned short* __restrict__ logitsbf,
                                                      const float* __restrict__ weights,
                                                      const float* __restrict__ p_trans,
                                                      const float* __restrict__ trans_probs,
                                                      const float* __restrict__ probs,
                                                      const int* __restrict__ idxes,
                                                      const float* __restrict__ rowsum,
                                                      float* __restrict__ out) {
    __shared__ __align__(16) float ts[VCHUNK];

    const int bt  = blockIdx.x;          // 0..799
    const int c   = blockIdx.y;          // 0..7
    const int b   = bt / Tdim;
    const int tid = threadIdx.x;
    const int v0  = c * VCHUNK;

    const float pt = p_trans[bt];
    const float c1 = (1.f - pt) / rowsum[bt];

    float4* ts4 = (float4*)ts;
    const float4 z = make_float4(0.f, 0.f, 0.f, 0.f);
#pragma unroll
    for (int i = tid; i < VCHUNK / 4; i += 256) ts4[i] = z;
    __syncthreads();

    for (int i = tid; i < Sdim * Kk; i += 256) {
        float pv  = probs[b * (Sdim * Kk) + i];
        float tpv = trans_probs[b * (Sdim * Kk) + i];
        int   idx = idxes[b * (Sdim * Kk) + i];
        int   rel = idx - v0;
        if (pv > 0.05f && (unsigned)rel < (unsigned)VCHUNK) {
            float w = weights[bt * Sdim + (i >> 3)];
            atomicAdd(&ts[rel], w * tpv);
        }
    }
    __syncthreads();

    const short8* lrow8 = (const short8*)(logitsbf + (size_t)bt * Vdim + v0);
    float4* out4 = (float4*)(out + (size_t)bt * Vdim + v0);
#pragma unroll
    for (int i = tid; i < VCHUNK / 8; i += 256) {
        short8 x8 = lrow8[i];
        float4 t0 = ts4[i * 2];
        float4 t1 = ts4[i * 2 + 1];
        float4 o0, o1;
        o0.x = __logf(pt * t0.x + c1 * __expf(bf2f((unsigned short)x8[0])));
        o0.y = __logf(pt * t0.y + c1 * __expf(bf2f((unsigned short)x8[1])));
        o0.z = __logf(pt * t0.z + c1 * __expf(bf2f((unsigned short)x8[2])));
        o0.w = __logf(pt * t0.w + c1 * __expf(bf2f((unsigned short)x8[3])));
        o1.x = __logf(pt * t1.x + c1 * __expf(bf2f((unsigned short)x8[4])));
        o1.y = __logf(pt * t1.y + c1 * __expf(bf2f((unsigned short)x8[5])));
        o1.z = __logf(pt * t1.z + c1 * __expf(bf2f((unsigned short)x8[6])));
        o1.w = __logf(pt * t1.w + c1 * __expf(bf2f((unsigned short)x8[7])));
        out4[i * 2]     = o0;
        out4[i * 2 + 1] = o1;
    }
}

extern "C" void kernel_launch(void* const* d_in, const int* in_sizes, int n_in,
                              void* d_out, int out_size, void* d_ws, size_t ws_size,
                              hipStream_t stream) {
    const float* dec_out     = (const float*)d_in[0];   // (8,100,512)
    const float* W           = (const float*)d_in[1];   // (512,32000)
    const float* bias        = (const float*)d_in[2];   // (32000,)
    const float* weights     = (const float*)d_in[3];   // (8,100,400)
    const float* p_trans     = (const float*)d_in[4];   // (8,100,1)
    const float* trans_probs = (const float*)d_in[5];   // (8,400,8)
    const float* probs       = (const float*)d_in[6];   // (8,400,8)
    const int*   idxes       = (const int*)d_in[7];     // (8,400,8)
    float* out = (float*)d_out;

    char* wsb = (char*)d_ws;
    unsigned short* Abf      = (unsigned short*)wsb;                      // 819,200 B
    unsigned short* WT       = (unsigned short*)(wsb + (1ull << 20));     // 32.8 MB
    unsigned short* logitsbf = (unsigned short*)(wsb + (35ull << 20));    // 51.2 MB
    float*          rowsum   = (float*)(wsb + (90ull << 20));             // 3200 B

    convert_a_kernel<<<dim3((Mdim * Hdim / 4 + 255) / 256), dim3(256), 0, stream>>>(dec_out, Abf, rowsum, Mdim * Hdim / 4);
    transpose_kernel<<<dim3(Vdim / 64, Hdim / 64), dim3(256), 0, stream>>>(W, WT);
    gemm_kernel<<<dim3(7 * 250), dim3(256), 0, stream>>>(Abf, WT, bias, logitsbf, rowsum);
    combine_kernel<<<dim3(Mdim, Vdim / VCHUNK), dim3(256), 0, stream>>>(logitsbf, weights, p_trans, trans_probs,
                                                                        probs, idxes, rowsum, out);
}

// Round 9
// 281.510 us; speedup vs baseline: 1.1316x; 1.0069x over previous
//
#include <hip/hip_runtime.h>

#define Bdim 8
#define Tdim 100
#define Sdim 400
#define Kk   8
#define Hdim 512
#define Vdim 32000
#define Mdim 800          // B*T
#define VCHUNK 4000       // vocab slice per combine block

typedef __attribute__((ext_vector_type(8))) short short8;     // 8 bf16 = 4 VGPRs
typedef __attribute__((ext_vector_type(4))) short short4v;    // 4 bf16 = 2 VGPRs
typedef __attribute__((ext_vector_type(4))) float float4_t;   // MFMA acc

static __device__ __forceinline__ unsigned short f2bf(float f) {
    unsigned int x = __float_as_uint(f);
    return (unsigned short)((x + 0x7fffu + ((x >> 16) & 1u)) >> 16);   // RNE
}
static __device__ __forceinline__ float bf2f(unsigned short h) {
    return __uint_as_float(((unsigned int)h) << 16);
}

// async 16B global->LDS (wave-uniform LDS base + lane*16)
static __device__ __forceinline__ void gload_lds16(const void* g, void* s) {
    __builtin_amdgcn_global_load_lds((const __attribute__((address_space(1))) void*)g,
                                     (__attribute__((address_space(3))) void*)s, 16, 0, 0);
}

// ---------------- prep: dec_out fp32 -> bf16 (vectorized x4); also zeros rowsum ----------------
__global__ void convert_a_kernel(const float* __restrict__ A, unsigned short* __restrict__ Abf,
                                 float* __restrict__ rowsum, int n4) {
    int i = blockIdx.x * blockDim.x + threadIdx.x;
    if (i < Mdim) rowsum[i] = 0.f;
    if (i < n4) {
        float4 f = ((const float4*)A)[i];
        short4v s;
        s[0] = (short)f2bf(f.x); s[1] = (short)f2bf(f.y);
        s[2] = (short)f2bf(f.z); s[3] = (short)f2bf(f.w);
        *(short4v*)(Abf + i * 4) = s;
    }
}

// ---------------- prep: W (512 x 32000) fp32 -> WT (32000 x 512) bf16 ----------------
__global__ __launch_bounds__(256) void transpose_kernel(const float* __restrict__ W,
                                                        unsigned short* __restrict__ WT) {
    __shared__ float tile[64][65];
    const int k0 = blockIdx.y * 64;
    const int v0 = blockIdx.x * 64;
    const int t  = threadIdx.x;
    const int tx = t & 15;            // float4 col within tile row
    const int ty = t >> 4;            // 0..15
#pragma unroll
    for (int i = 0; i < 64; i += 16) {
        float4 f = *(const float4*)&W[(size_t)(k0 + ty + i) * Vdim + v0 + tx * 4];
        tile[ty + i][tx * 4 + 0] = f.x;
        tile[ty + i][tx * 4 + 1] = f.y;
        tile[ty + i][tx * 4 + 2] = f.z;
        tile[ty + i][tx * 4 + 3] = f.w;
    }
    __syncthreads();
    const int c = t & 7;              // k-chunk of 8
    const int v = t >> 3;             // 0..31
#pragma unroll
    for (int i = 0; i < 64; i += 32) {
        short8 s;
#pragma unroll
        for (int j = 0; j < 8; ++j) s[j] = (short)f2bf(tile[c * 8 + j][v + i]);
        *(short8*)&WT[(size_t)(v0 + v + i) * Hdim + k0 + c * 8] = s;
    }
}

// ---------------- GEMM: logits(800x32000) = Abf * WT^T + bias; bf16 store + row sumexp ----
// Round-9: 8-wave split of the verified R8 kernel. Diagnosis: R8 occupancy 17% =
// 1.4 waves/SIMD -- every ds_read/barrier stall fully exposed. Same 128x128 tile, same
// 64 KB dbuf LDS, same depth-2 counted pipeline, but 512 threads (8 waves, 4m x 2n,
// 32x64 output each): 2 blocks/CU = 4 waves/SIMD, half per-wave work, same barrier count.
//   prologue: stage(0)->buf0, stage(1)->buf1          (4 gload_lds per thread per stage)
//   per kt:  vmcnt(4) [kt<7] / vmcnt(0) [kt==7]   -> stage(kt) provably retired
//            s_barrier -> compute(kt) -> s_barrier -> stage(kt+2) [kt<6]
__global__ __launch_bounds__(512, 4) void gemm_kernel(const unsigned short* __restrict__ Abf,
                                                      const unsigned short* __restrict__ WT,
                                                      const float* __restrict__ bias,
                                                      unsigned short* __restrict__ logitsbf,
                                                      float* __restrict__ rowsum) {
    __shared__ __align__(16) unsigned short As[2 * 128 * 64];   // 2 x 16 KB
    __shared__ __align__(16) unsigned short Bs[2 * 128 * 64];   // 2 x 16 KB

    const int tid  = threadIdx.x;
    const int lane = tid & 63;
    const int wave = tid >> 6;             // 0..7
    const int l15  = lane & 15;
    const int kq   = lane >> 4;            // 0..3

    // bijective XCD swizzle (m204): nwg = 7*250 = 1750
    const int NWG = 7 * 250;
    const int orig = blockIdx.x;
    const int xcd = orig & 7;
    const int q8  = NWG >> 3;              // 218
    const int r8  = NWG & 7;               // 6
    const int wg  = (xcd < r8 ? xcd * (q8 + 1) : r8 * (q8 + 1) + (xcd - r8) * q8) + (orig >> 3);
    const int m_blk = (wg % 7) * 128;      // m-fastest: B-panel reuse is L2-local
    const int n_blk = (wg / 7) * 128;

    const int wm = wave & 3, wn = wave >> 2;   // 4m x 2n wave grid
    const int m0 = wm * 32, n0 = wn * 64;      // per-wave 32x64 output

    // staging: 1024 16B-chunks per matrix; chunk = (q*8+wave)*64 + lane, q=0..1
    const unsigned short* agp[2];
    const unsigned short* bgp[2];
    int lslot[2];
#pragma unroll
    for (int q = 0; q < 2; ++q) {
        int chunk = (q * 8 + wave) * 64 + lane;
        int row = chunk >> 3, c = chunk & 7;
        int gc  = c ^ (row & 7);                 // XOR swizzle: lane fetches the chunk that
        int arow = m_blk + row;                  // belongs at its contiguous LDS slot
        if (arow >= Mdim) arow = Mdim - 1;       // clamp; epilogue masks
        agp[q] = Abf + (size_t)arow * Hdim + gc * 8;
        bgp[q] = WT + (size_t)(n_blk + row) * Hdim + gc * 8;
        lslot[q] = (q * 8 + wave) * 512;         // wave-uniform base (shorts)
    }

    // fragment LDS offsets (shorts): row*64 + ((ks*4+kq)^(row&7))*8
    int a_off[2][2], b_off[2][4];
#pragma unroll
    for (int ks = 0; ks < 2; ++ks) {
#pragma unroll
        for (int i = 0; i < 2; ++i) {
            int ra = m0 + i * 16 + l15;
            a_off[ks][i] = ra * 64 + (((ks * 4 + kq) ^ (ra & 7)) * 8);
        }
#pragma unroll
        for (int j = 0; j < 4; ++j) {
            int rb = n0 + j * 16 + l15;
            b_off[ks][j] = rb * 64 + (((ks * 4 + kq) ^ (rb & 7)) * 8);
        }
    }

    float4_t acc[2][4] = {};

    // prologue: stage K-tiles 0 and 1 into buffers 0 and 1
#pragma unroll
    for (int q = 0; q < 2; ++q) {
        gload_lds16(agp[q], As + lslot[q]);
        gload_lds16(bgp[q], Bs + lslot[q]);
    }
#pragma unroll
    for (int q = 0; q < 2; ++q) {
        gload_lds16(agp[q] + 64, As + 8192 + lslot[q]);
        gload_lds16(bgp[q] + 64, Bs + 8192 + lslot[q]);
    }

#pragma unroll
    for (int kt = 0; kt < 8; ++kt) {
        const int cur = kt & 1;
        // stage(kt) must be retired before compute(kt). For kt<7 there are >4 loads in
        // flight so vmcnt(4) pins exactly stage(kt); at kt==7 only stage(7)'s 4 remain,
        // so the wait must be vmcnt(0) (R7's lesson).
        if (kt == 7) asm volatile("s_waitcnt vmcnt(0)" ::: "memory");
        else         asm volatile("s_waitcnt vmcnt(4)" ::: "memory");
        __builtin_amdgcn_s_barrier();            // buf(cur) now valid across all waves
        __builtin_amdgcn_sched_barrier(0);
        const unsigned short* Ab = As + cur * 8192;
        const unsigned short* Bb = Bs + cur * 8192;
#pragma unroll
        for (int ks = 0; ks < 2; ++ks) {
            short8 af[2], bfr[4];
#pragma unroll
            for (int i = 0; i < 2; ++i) af[i]  = *(const short8*)(Ab + a_off[ks][i]);
#pragma unroll
            for (int j = 0; j < 4; ++j) bfr[j] = *(const short8*)(Bb + b_off[ks][j]);
#pragma unroll
            for (int i = 0; i < 2; ++i)
#pragma unroll
                for (int j = 0; j < 4; ++j)
                    acc[i][j] = __builtin_amdgcn_mfma_f32_16x16x32_bf16(af[i], bfr[j], acc[i][j], 0, 0, 0);
        }
        if (kt < 7) __builtin_amdgcn_s_barrier();  // all waves done reading buf(cur)
        if (kt < 6) {                              // stage(kt+2) -> buf(cur), WAR-safe
            const int ko = (kt + 2) * 64;
#pragma unroll
            for (int q = 0; q < 2; ++q) {
                gload_lds16(agp[q] + ko, As + cur * 8192 + lslot[q]);
                gload_lds16(bgp[q] + ko, Bs + cur * 8192 + lslot[q]);
            }
        }
    }

    // epilogue: bias add, bf16 store, per-row partial sum of exp -> atomicAdd rowsum
    float bj[4];
#pragma unroll
    for (int j = 0; j < 4; ++j) bj[j] = bias[n_blk + n0 + j * 16 + l15];

#pragma unroll
    for (int i = 0; i < 2; ++i) {
        float se[4] = {0.f, 0.f, 0.f, 0.f};
        int grow0 = m_blk + m0 + i * 16 + kq * 4;      // + r
#pragma unroll
        for (int j = 0; j < 4; ++j) {
            int col = n_blk + n0 + j * 16 + l15;
#pragma unroll
            for (int r = 0; r < 4; ++r) {
                float v = acc[i][j][r] + bj[j];
                se[r] += __expf(v);
                if (grow0 + r < Mdim)
                    logitsbf[(size_t)(grow0 + r) * Vdim + col] = f2bf(v);
            }
        }
#pragma unroll
        for (int r = 0; r < 4; ++r) {
#pragma unroll
            for (int off = 8; off; off >>= 1)
                se[r] += __shfl_xor(se[r], off, 64);   // reduce over the 16 cols (l15)
        }
        if (l15 == 0) {
#pragma unroll
            for (int r = 0; r < 4; ++r)
                if (grow0 + r < Mdim) atomicAdd(&rowsum[grow0 + r], se[r]);
        }
    }
}

// ---------------- combine: sparse copy-dist scatter + log blend ----------------
__global__ __launch_bounds__(256) void combine_kernel(const unsigned short* __restrict__ logitsbf,
                                                      const float* __restrict__ weights,
                                                      const float* __restrict__ p_trans,
                                                      const float* __restrict__ trans_probs,
                                                      const float* __restrict__ probs,
                                                      const int* __restrict__ idxes,
                                                      const float* __restrict__ rowsum,
                                                      float* __restrict__ out) {
    __shared__ __align__(16) float ts[VCHUNK];

    const int bt  = blockIdx.x;          // 0..799
    const int c   = blockIdx.y;          // 0..7
    const int b   = bt / Tdim;
    const int tid = threadIdx.x;
    const int v0  = c * VCHUNK;

    const float pt = p_trans[bt];
    const float c1 = (1.f - pt) / rowsum[bt];

    float4* ts4 = (float4*)ts;
    const float4 z = make_float4(0.f, 0.f, 0.f, 0.f);
#pragma unroll
    for (int i = tid; i < VCHUNK / 4; i += 256) ts4[i] = z;
    __syncthreads();

    for (int i = tid; i < Sdim * Kk; i += 256) {
        float pv  = probs[b * (Sdim * Kk) + i];
        float tpv = trans_probs[b * (Sdim * Kk) + i];
        int   idx = idxes[b * (Sdim * Kk) + i];
        int   rel = idx - v0;
        if (pv > 0.05f && (unsigned)rel < (unsigned)VCHUNK) {
            float w = weights[bt * Sdim + (i >> 3)];
            atomicAdd(&ts[rel], w * tpv);
        }
    }
    __syncthreads();

    const short8* lrow8 = (const short8*)(logitsbf + (size_t)bt * Vdim + v0);
    float4* out4 = (float4*)(out + (size_t)bt * Vdim + v0);
#pragma unroll
    for (int i = tid; i < VCHUNK / 8; i += 256) {
        short8 x8 = lrow8[i];
        float4 t0 = ts4[i * 2];
        float4 t1 = ts4[i * 2 + 1];
        float4 o0, o1;
        o0.x = __logf(pt * t0.x + c1 * __expf(bf2f((unsigned short)x8[0])));
        o0.y = __logf(pt * t0.y + c1 * __expf(bf2f((unsigned short)x8[1])));
        o0.z = __logf(pt * t0.z + c1 * __expf(bf2f((unsigned short)x8[2])));
        o0.w = __logf(pt * t0.w + c1 * __expf(bf2f((unsigned short)x8[3])));
        o1.x = __logf(pt * t1.x + c1 * __expf(bf2f((unsigned short)x8[4])));
        o1.y = __logf(pt * t1.y + c1 * __expf(bf2f((unsigned short)x8[5])));
        o1.z = __logf(pt * t1.z + c1 * __expf(bf2f((unsigned short)x8[6])));
        o1.w = __logf(pt * t1.w + c1 * __expf(bf2f((unsigned short)x8[7])));
        out4[i * 2]     = o0;
        out4[i * 2 + 1] = o1;
    }
}

extern "C" void kernel_launch(void* const* d_in, const int* in_sizes, int n_in,
                              void* d_out, int out_size, void* d_ws, size_t ws_size,
                              hipStream_t stream) {
    const float* dec_out     = (const float*)d_in[0];   // (8,100,512)
    const float* W           = (const float*)d_in[1];   // (512,32000)
    const float* bias        = (const float*)d_in[2];   // (32000,)
    const float* weights     = (const float*)d_in[3];   // (8,100,400)
    const float* p_trans     = (const float*)d_in[4];   // (8,100,1)
    const float* trans_probs = (const float*)d_in[5];   // (8,400,8)
    const float* probs       = (const float*)d_in[6];   // (8,400,8)
    const int*   idxes       = (const int*)d_in[7];     // (8,400,8)
    float* out = (float*)d_out;

    char* wsb = (char*)d_ws;
    unsigned short* Abf      = (unsigned short*)wsb;                      // 819,200 B
    unsigned short* WT       = (unsigned short*)(wsb + (1ull << 20));     // 32.8 MB
    unsigned short* logitsbf = (unsigned short*)(wsb + (35ull << 20));    // 51.2 MB
    float*          rowsum   = (float*)(wsb + (90ull << 20));             // 3200 B

    convert_a_kernel<<<dim3((Mdim * Hdim / 4 + 255) / 256), dim3(256), 0, stream>>>(dec_out, Abf, rowsum, Mdim * Hdim / 4);
    transpose_kernel<<<dim3(Vdim / 64, Hdim / 64), dim3(256), 0, stream>>>(W, WT);
    gemm_kernel<<<dim3(7 * 250), dim3(512), 0, stream>>>(Abf, WT, bias, logitsbf, rowsum);
    combine_kernel<<<dim3(Mdim, Vdim / VCHUNK), dim3(256), 0, stream>>>(logitsbf, weights, p_trans, trans_probs,
                                                                        probs, idxes, rowsum, out);
}